// Round 1
// baseline (199.042 us; speedup 1.0000x reference)
//
#include <hip/hip_runtime.h>
#include <math.h>

#define N_TOTAL 8192
#define BATCH   4096
#define DIMS    64

// ws layout:
//   double wd[0]      : sum of squared norms (Σ‖x‖²)
//   double wd[1..64]  : per-column sums (64)
//   double wd[65]     : grand signed kernel sum
//   float  wf[0]      : scale = 1/(bw0 * ln2)   (wf = (float*)(wd+66))
//   float  sqbuf[8192]: per-row squared norms    (sqbuf = wf+2)

#if defined(__has_builtin)
#if __has_builtin(__builtin_amdgcn_exp2f)
#define EXP2F(x) __builtin_amdgcn_exp2f(x)
#endif
#endif
#ifndef EXP2F
#define EXP2F(x) exp2f(x)
#endif

__global__ __launch_bounds__(256) void pass1_kernel(const float* __restrict__ src,
                                                    const float* __restrict__ tgt,
                                                    double* __restrict__ wd,
                                                    float* __restrict__ sqbuf) {
    const int lane = threadIdx.x & 63;
    const int wave = threadIdx.x >> 6;
    const int gw = blockIdx.x * 4 + wave;
    const int numWaves = gridDim.x * 4;

    double colacc = 0.0;
    double sqacc = 0.0;
    for (int r = gw; r < N_TOTAL; r += numWaves) {
        const float* row = (r < BATCH) ? (src + (size_t)r * DIMS)
                                       : (tgt + (size_t)(r - BATCH) * DIMS);
        float x = row[lane];
        colacc += (double)x;
        float s = x * x;
        // butterfly reduce across the 64-lane wave
        #pragma unroll
        for (int off = 32; off > 0; off >>= 1) s += __shfl_xor(s, off, 64);
        if (lane == 0) sqbuf[r] = s;
        sqacc += (double)s;
    }
    if (lane == 0) atomicAdd(&wd[0], sqacc);
    atomicAdd(&wd[1 + lane], colacc);
}

__global__ void finalize1_kernel(double* __restrict__ wd, float* __restrict__ wf) {
    double sumsq = wd[0];
    double s2 = 0.0;
    for (int c = 0; c < 64; ++c) { double v = wd[1 + c]; s2 += v * v; }
    const double n = (double)N_TOTAL;
    double sumL2 = 2.0 * n * sumsq - 2.0 * s2;           // Σ_ij L2_ij exactly
    double bandwidth = sumL2 / (n * n - n);
    double bw0 = bandwidth / 4.0;                        // / KERNEL_MUL^(KERNEL_NUM//2)
    wf[0] = (float)(1.0 / (bw0 * 0.6931471805599453));   // exp2 scale
}

__global__ __launch_bounds__(256) void pass2_kernel(const float* __restrict__ src,
                                                    const float* __restrict__ tgt,
                                                    const float* __restrict__ sqbuf,
                                                    const float* __restrict__ wf,
                                                    double* __restrict__ grand) {
    const int br = blockIdx.y, bc = blockIdx.x;
    if (bc < br) return;  // symmetric: only upper-triangle tiles

    __shared__ __align__(16) float As[DIMS][68];  // [k][m], pitch 68 -> 16B-aligned rows
    __shared__ __align__(16) float Bs[DIMS][68];
    __shared__ float sqa_s[64], sqb_s[64];
    __shared__ float wsum[4];

    const int t = threadIdx.x;

    if (t < 64)       sqa_s[t]      = sqbuf[br * 64 + t];
    else if (t < 128) sqb_s[t - 64] = sqbuf[bc * 64 + (t - 64)];

    // stage 64x64 A/B tiles into LDS, transposed to [k][m]
    #pragma unroll
    for (int it = 0; it < 4; ++it) {
        int q  = t + 256 * it;
        int r  = q >> 4;           // row within tile 0..63
        int c4 = (q & 15) << 2;    // col 0..60 step 4
        int gra = br * 64 + r;
        const float* rowa = (gra < BATCH) ? (src + (size_t)gra * DIMS)
                                          : (tgt + (size_t)(gra - BATCH) * DIMS);
        float4 va = *(const float4*)(rowa + c4);
        As[c4 + 0][r] = va.x; As[c4 + 1][r] = va.y;
        As[c4 + 2][r] = va.z; As[c4 + 3][r] = va.w;
        int grb = bc * 64 + r;
        const float* rowb = (grb < BATCH) ? (src + (size_t)grb * DIMS)
                                          : (tgt + (size_t)(grb - BATCH) * DIMS);
        float4 vb = *(const float4*)(rowb + c4);
        Bs[c4 + 0][r] = vb.x; Bs[c4 + 1][r] = vb.y;
        Bs[c4 + 2][r] = vb.z; Bs[c4 + 3][r] = vb.w;
    }
    const float scale = wf[0];
    __syncthreads();

    const int m0 = (t & 15) << 2;
    const int n0 = (t >> 4) << 2;

    float acc[4][4];
    #pragma unroll
    for (int i = 0; i < 4; ++i)
        #pragma unroll
        for (int j = 0; j < 4; ++j) acc[i][j] = 0.f;

    #pragma unroll 8
    for (int k = 0; k < DIMS; ++k) {
        float4 a = *(const float4*)&As[k][m0];
        float4 b = *(const float4*)&Bs[k][n0];
        float am[4] = {a.x, a.y, a.z, a.w};
        float bn[4] = {b.x, b.y, b.z, b.w};
        #pragma unroll
        for (int i = 0; i < 4; ++i)
            #pragma unroll
            for (int j = 0; j < 4; ++j)
                acc[i][j] = fmaf(am[i], bn[j], acc[i][j]);
    }

    float lsum = 0.f;
    #pragma unroll
    for (int i = 0; i < 4; ++i) {
        float sa = sqa_s[m0 + i];
        #pragma unroll
        for (int j = 0; j < 4; ++j) {
            float L2 = sa + sqb_s[n0 + j] - 2.f * acc[i][j];
            float t0 = -L2 * scale;   // exp2 domain
            lsum += EXP2F(t0) + EXP2F(t0 * 0.5f) + EXP2F(t0 * 0.25f)
                  + EXP2F(t0 * 0.125f) + EXP2F(t0 * 0.0625f);
        }
    }

    // reduce within wave, then across the 4 waves
    #pragma unroll
    for (int off = 32; off > 0; off >>= 1) lsum += __shfl_xor(lsum, off, 64);
    const int lane = t & 63, wv = t >> 6;
    if (lane == 0) wsum[wv] = lsum;
    __syncthreads();
    if (t == 0) {
        float bsum = (wsum[0] + wsum[1]) + (wsum[2] + wsum[3]);
        float sgn = ((br < 64) == (bc < 64)) ? 1.f : -1.f;  // quadrant sign
        float w   = (br == bc) ? 1.f : 2.f;                 // symmetry weight
        atomicAdd(grand, (double)(bsum * sgn * w));
    }
}

__global__ void finalize2_kernel(const double* __restrict__ grand, float* __restrict__ out) {
    out[0] = (float)(grand[0] / ((double)BATCH * (double)BATCH));
}

extern "C" void kernel_launch(void* const* d_in, const int* in_sizes, int n_in,
                              void* d_out, int out_size, void* d_ws, size_t ws_size,
                              hipStream_t stream) {
    const float* src = (const float*)d_in[0];
    const float* tgt = (const float*)d_in[1];
    double* wd = (double*)d_ws;
    float* wf = (float*)(wd + 66);
    float* sqbuf = wf + 2;

    // zero the accumulators (ws is poisoned 0xAA before every launch)
    hipMemsetAsync(d_ws, 0, 66 * sizeof(double), stream);

    pass1_kernel<<<128, 256, 0, stream>>>(src, tgt, wd, sqbuf);
    finalize1_kernel<<<1, 1, 0, stream>>>(wd, wf);

    dim3 grid(128, 128);
    pass2_kernel<<<grid, 256, 0, stream>>>(src, tgt, sqbuf, wf, &wd[65]);

    finalize2_kernel<<<1, 1, 0, stream>>>(&wd[65], (float*)d_out);
}

// Round 2
// 177.368 us; speedup vs baseline: 1.1222x; 1.1222x over previous
//
#include <hip/hip_runtime.h>
#include <math.h>

#define N_TOTAL 8192
#define BATCH   4096
#define DIMS    64

// ws layout:
//   double wd[0]      : sum of squared norms
//   double wd[1..64]  : per-column sums
//   double wd[65]     : grand signed kernel sum
//   float  sqbuf[8192]: per-row squared norms  (starts at wd+66)

#if defined(__has_builtin)
#if __has_builtin(__builtin_amdgcn_exp2f)
#define EXP2F(x) __builtin_amdgcn_exp2f(x)
#endif
#endif
#ifndef EXP2F
#define EXP2F(x) exp2f(x)
#endif

typedef __attribute__((ext_vector_type(8))) short bf16x8;
typedef __attribute__((ext_vector_type(4))) float f32x4;
typedef __attribute__((ext_vector_type(4))) short s16x4;

__device__ inline short f2bf_rn(float x) {
    unsigned u = __float_as_uint(x);
    unsigned r = (u + 0x7fffu + ((u >> 16) & 1u)) >> 16;
    return (short)r;
}
__device__ inline float bf2f(short h) {
    return __uint_as_float(((unsigned)(unsigned short)h) << 16);
}

__global__ __launch_bounds__(256) void pass1_kernel(const float* __restrict__ src,
                                                    const float* __restrict__ tgt,
                                                    double* __restrict__ wd,
                                                    float* __restrict__ sqbuf) {
    __shared__ double cred[4][64];
    __shared__ double sred[4];
    const int lane = threadIdx.x & 63;
    const int wv = threadIdx.x >> 6;
    const int gw = blockIdx.x * 4 + wv;
    const int numWaves = gridDim.x * 4;

    double colacc = 0.0, sqacc = 0.0;
    for (int r = gw; r < N_TOTAL; r += numWaves) {
        const float* row = (r < BATCH) ? (src + (size_t)r * DIMS)
                                       : (tgt + (size_t)(r - BATCH) * DIMS);
        float x = row[lane];
        colacc += (double)x;
        float s = x * x;
        #pragma unroll
        for (int off = 32; off > 0; off >>= 1) s += __shfl_xor(s, off, 64);
        if (lane == 0) { sqbuf[r] = s; sqacc += (double)s; }
    }
    cred[wv][lane] = colacc;
    if (lane == 0) sred[wv] = sqacc;
    __syncthreads();
    if (wv == 0) {
        double c = (cred[0][lane] + cred[1][lane]) + (cred[2][lane] + cred[3][lane]);
        atomicAdd(&wd[1 + lane], c);
        if (lane == 0) atomicAdd(&wd[0], (sred[0] + sred[1]) + (sred[2] + sred[3]));
    }
}

__global__ __launch_bounds__(256) void pass2_kernel(const float* __restrict__ src,
                                                    const float* __restrict__ tgt,
                                                    const float* __restrict__ sqbuf,
                                                    const double* __restrict__ wd,
                                                    double* __restrict__ grand) {
    const int br = blockIdx.y, bc = blockIdx.x;
    if (bc < br) return;  // symmetric: upper triangle only

    // pitch 72 bf16 = 144 B per row: 16B-aligned rows, 36 words ≡ 4 (mod 32)
    // -> uniform bank load for both b64 writes and b128 frag reads
    __shared__ __align__(16) short Ah[64][72];
    __shared__ __align__(16) short Al[64][72];
    __shared__ __align__(16) short Bh[64][72];
    __shared__ __align__(16) short Bl[64][72];
    __shared__ float sqa_s[64], sqb_s[64];
    __shared__ float s_c;     // -1/(16 * bw0 * ln2)
    __shared__ float wsum[4];

    const int t = threadIdx.x;

    if (t == 0) {  // bandwidth from pass1 sums (replaces finalize kernel)
        double sumsq = wd[0], s2 = 0.0;
        for (int c = 0; c < 64; ++c) { double v = wd[1 + c]; s2 += v * v; }
        const double n = (double)N_TOTAL;
        double bw0 = (2.0 * n * sumsq - 2.0 * s2) / (n * n - n) / 4.0;
        s_c = (float)(-1.0 / (bw0 * 0.6931471805599453 * 16.0));
    }
    if (t < 64)       sqa_s[t]      = sqbuf[br * 64 + t];
    else if (t < 128) sqb_s[t - 64] = sqbuf[bc * 64 + (t - 64)];

    // stage tiles: row-major [sample][k], fp32 -> bf16 hi + bf16 lo
    #pragma unroll
    for (int it = 0; it < 4; ++it) {
        int q = t + 256 * it;
        int r = q >> 4;            // sample row within tile
        int c4 = (q & 15) << 2;    // k offset
        {
            int g = br * 64 + r;
            const float* row = (g < BATCH) ? (src + (size_t)g * DIMS)
                                           : (tgt + (size_t)(g - BATCH) * DIMS);
            float4 v = *(const float4*)(row + c4);
            float xs[4] = {v.x, v.y, v.z, v.w};
            s16x4 h, l;
            #pragma unroll
            for (int i = 0; i < 4; ++i) {
                short hh = f2bf_rn(xs[i]);
                h[i] = hh;
                l[i] = f2bf_rn(xs[i] - bf2f(hh));
            }
            *(s16x4*)&Ah[r][c4] = h;
            *(s16x4*)&Al[r][c4] = l;
        }
        {
            int g = bc * 64 + r;
            const float* row = (g < BATCH) ? (src + (size_t)g * DIMS)
                                           : (tgt + (size_t)(g - BATCH) * DIMS);
            float4 v = *(const float4*)(row + c4);
            float xs[4] = {v.x, v.y, v.z, v.w};
            s16x4 h, l;
            #pragma unroll
            for (int i = 0; i < 4; ++i) {
                short hh = f2bf_rn(xs[i]);
                h[i] = hh;
                l[i] = f2bf_rn(xs[i] - bf2f(hh));
            }
            *(s16x4*)&Bh[r][c4] = h;
            *(s16x4*)&Bl[r][c4] = l;
        }
    }
    __syncthreads();

    const int lane = t & 63, w = t >> 6;
    const int quad = lane >> 4, lrow = lane & 15;

    // A-frags for this wave's 16-row block (kc = k-chunk of 32)
    const short* abase_h = &Ah[w * 16 + lrow][0] + quad * 8;
    const short* abase_l = &Al[w * 16 + lrow][0] + quad * 8;
    bf16x8 ah0 = *(const bf16x8*)(abase_h);
    bf16x8 ah1 = *(const bf16x8*)(abase_h + 32);
    bf16x8 al0 = *(const bf16x8*)(abase_l);
    bf16x8 al1 = *(const bf16x8*)(abase_l + 32);

    f32x4 acc[4];
    #pragma unroll
    for (int j = 0; j < 4; ++j) acc[j] = (f32x4){0.f, 0.f, 0.f, 0.f};

    #pragma unroll
    for (int j = 0; j < 4; ++j) {
        const short* bbase_h = &Bh[j * 16 + lrow][0] + quad * 8;
        const short* bbase_l = &Bl[j * 16 + lrow][0] + quad * 8;
        bf16x8 bh0 = *(const bf16x8*)(bbase_h);
        bf16x8 bh1 = *(const bf16x8*)(bbase_h + 32);
        bf16x8 bl0 = *(const bf16x8*)(bbase_l);
        bf16x8 bl1 = *(const bf16x8*)(bbase_l + 32);
        // dot = Ah·Bh + Ah·Bl + Al·Bh  (lo·lo dropped: ~2^-18 rel)
        acc[j] = __builtin_amdgcn_mfma_f32_16x16x32_bf16(ah0, bh0, acc[j], 0, 0, 0);
        acc[j] = __builtin_amdgcn_mfma_f32_16x16x32_bf16(ah1, bh1, acc[j], 0, 0, 0);
        acc[j] = __builtin_amdgcn_mfma_f32_16x16x32_bf16(ah0, bl0, acc[j], 0, 0, 0);
        acc[j] = __builtin_amdgcn_mfma_f32_16x16x32_bf16(ah1, bl1, acc[j], 0, 0, 0);
        acc[j] = __builtin_amdgcn_mfma_f32_16x16x32_bf16(al0, bh0, acc[j], 0, 0, 0);
        acc[j] = __builtin_amdgcn_mfma_f32_16x16x32_bf16(al1, bh1, acc[j], 0, 0, 0);
    }

    const float c = s_c;
    float lsum = 0.f;
    #pragma unroll
    for (int j = 0; j < 4; ++j) {
        float sb = sqb_s[j * 16 + lrow];
        #pragma unroll
        for (int p = 0; p < 4; ++p) {
            float sa = sqa_s[w * 16 + quad * 4 + p];   // C/D: row=quad*4+reg, col=lane&15
            float L2 = fmaf(-2.f, acc[j][p], sa + sb);
            // exp2(t/16) then 4 squarings replaces 5 transcendentals
            float e4 = EXP2F(L2 * c);
            float e3 = e4 * e4;
            float e2 = e3 * e3;
            float e1 = e2 * e2;
            float e0 = e1 * e1;
            lsum += ((e0 + e1) + (e2 + e3)) + e4;
        }
    }

    #pragma unroll
    for (int off = 32; off > 0; off >>= 1) lsum += __shfl_xor(lsum, off, 64);
    if (lane == 0) wsum[w] = lsum;
    __syncthreads();
    if (t == 0) {
        float bsum = (wsum[0] + wsum[1]) + (wsum[2] + wsum[3]);
        float sgn = ((br < 64) == (bc < 64)) ? 1.f : -1.f;
        float wt  = (br == bc) ? 1.f : 2.f;
        atomicAdd(grand, (double)(bsum * sgn * wt));
    }
}

__global__ void finalize2_kernel(const double* __restrict__ grand, float* __restrict__ out) {
    out[0] = (float)(grand[0] / ((double)BATCH * (double)BATCH));
}

extern "C" void kernel_launch(void* const* d_in, const int* in_sizes, int n_in,
                              void* d_out, int out_size, void* d_ws, size_t ws_size,
                              hipStream_t stream) {
    const float* src = (const float*)d_in[0];
    const float* tgt = (const float*)d_in[1];
    double* wd = (double*)d_ws;
    float* sqbuf = (float*)(wd + 66);

    hipMemsetAsync(d_ws, 0, 66 * sizeof(double), stream);

    pass1_kernel<<<256, 256, 0, stream>>>(src, tgt, wd, sqbuf);

    dim3 grid(128, 128);
    pass2_kernel<<<grid, 256, 0, stream>>>(src, tgt, sqbuf, wd, &wd[65]);

    finalize2_kernel<<<&wd[65] == nullptr ? 1 : 1, 1, 0, stream>>>(&wd[65], (float*)d_out);
}

// Round 3
// 116.862 us; speedup vs baseline: 1.7032x; 1.5178x over previous
//
#include <hip/hip_runtime.h>
#include <math.h>

#define N_TOTAL 8192
#define BATCH   4096
#define DIMS    64
#define LIVE_BLOCKS 1088   // sum_{bc=0}^{127} (bc/8 + 1)

// ws layout (bytes):
//   0       double wd[66]   (0=sum of sq norms, 1..64=col sums, 65=grand)
//   528     int counter     (pad to 544)
//   544     float  sq[8192]
//   33312   short  Xh[8192*64]   (bf16 hi, row-major)
//   1081888 short  Xl[8192*64]   (bf16 lo, row-major)

#if defined(__has_builtin)
#if __has_builtin(__builtin_amdgcn_exp2f)
#define EXP2F(x) __builtin_amdgcn_exp2f(x)
#endif
#endif
#ifndef EXP2F
#define EXP2F(x) exp2f(x)
#endif

typedef __attribute__((ext_vector_type(8))) short bf16x8;
typedef __attribute__((ext_vector_type(4))) float f32x4;
typedef __attribute__((ext_vector_type(4))) short s16x4;

__device__ inline short f2bf_rn(float x) {
    unsigned u = __float_as_uint(x);
    unsigned r = (u + 0x7fffu + ((u >> 16) & 1u)) >> 16;
    return (short)r;
}
__device__ inline float bf2f(short h) {
    return __uint_as_float(((unsigned)(unsigned short)h) << 16);
}

// pass1: fp32 -> bf16 hi/lo split (once), row sq-norms, col sums for bandwidth
__global__ __launch_bounds__(256) void pass1_kernel(const float* __restrict__ src,
                                                    const float* __restrict__ tgt,
                                                    double* __restrict__ wd,
                                                    float* __restrict__ sqbuf,
                                                    short* __restrict__ Xh,
                                                    short* __restrict__ Xl) {
    __shared__ double cred[4][64];
    __shared__ double sred[4];
    const int lane = threadIdx.x & 63;
    const int wv = threadIdx.x >> 6;
    const int sub = lane >> 4;          // row within group of 4
    const int k4 = (lane & 15) << 2;    // k offset (4 floats per lane)
    const int gw = blockIdx.x * 4 + wv;
    const int numWaves = gridDim.x * 4;

    double colacc[4] = {0.0, 0.0, 0.0, 0.0};
    double sqacc = 0.0;

    for (int g = gw; g < N_TOTAL / 4; g += numWaves) {
        int r = g * 4 + sub;
        const float* row = (r < BATCH) ? (src + (size_t)r * DIMS)
                                       : (tgt + (size_t)(r - BATCH) * DIMS);
        float4 v = *(const float4*)(row + k4);
        float xs[4] = {v.x, v.y, v.z, v.w};
        s16x4 h, l;
        float ssum = 0.f;
        #pragma unroll
        for (int i = 0; i < 4; ++i) {
            short hh = f2bf_rn(xs[i]);
            h[i] = hh;
            l[i] = f2bf_rn(xs[i] - bf2f(hh));
            colacc[i] += (double)xs[i];
            ssum = fmaf(xs[i], xs[i], ssum);
        }
        *(s16x4*)(Xh + (size_t)r * DIMS + k4) = h;
        *(s16x4*)(Xl + (size_t)r * DIMS + k4) = l;
        // row-norm: reduce across the 16 lanes of this row
        ssum += __shfl_xor(ssum, 1, 64);
        ssum += __shfl_xor(ssum, 2, 64);
        ssum += __shfl_xor(ssum, 4, 64);
        ssum += __shfl_xor(ssum, 8, 64);
        if ((lane & 15) == 0) { sqbuf[r] = ssum; sqacc += (double)ssum; }
    }
    // fold the 4 row-slots: lanes with same (lane&15) hold the same columns
    #pragma unroll
    for (int i = 0; i < 4; ++i) {
        colacc[i] += __shfl_xor(colacc[i], 16, 64);
        colacc[i] += __shfl_xor(colacc[i], 32, 64);
    }
    sqacc += __shfl_xor(sqacc, 16, 64);
    sqacc += __shfl_xor(sqacc, 32, 64);
    if (lane < 16) {
        #pragma unroll
        for (int i = 0; i < 4; ++i) cred[wv][lane * 4 + i] = colacc[i];
    }
    if (lane == 0) sred[wv] = sqacc;
    __syncthreads();
    if (wv == 0) {
        double c = (cred[0][lane] + cred[1][lane]) + (cred[2][lane] + cred[3][lane]);
        atomicAdd(&wd[1 + lane], c);
        if (lane == 0) atomicAdd(&wd[0], (sred[0] + sred[1]) + (sred[2] + sred[3]));
    }
}

// pass2: no LDS in hot loop; B-frags register-resident; direct global frag loads
__global__ __launch_bounds__(256, 4) void pass2_kernel(const short* __restrict__ Xh,
                                                       const short* __restrict__ Xl,
                                                       const float* __restrict__ sqbuf,
                                                       const double* __restrict__ wd,
                                                       double* __restrict__ grand,
                                                       int* __restrict__ cnt,
                                                       float* __restrict__ out) {
    const int bc = blockIdx.x;
    const int r0 = blockIdx.y * 8;
    if (r0 > bc) return;                       // upper triangle only
    int r1 = bc < r0 + 7 ? bc : r0 + 7;

    __shared__ float s_c_sh;
    __shared__ double s_wred[4];

    const int t = threadIdx.x;
    const int lane = t & 63, w = t >> 6;
    const int quad = lane >> 4, lrow = lane & 15;

    if (t == 0) {
        double sumsq = wd[0], s2 = 0.0;
        for (int c = 0; c < 64; ++c) { double v = wd[1 + c]; s2 += v * v; }
        const double n = (double)N_TOTAL;
        double bw0 = (2.0 * n * sumsq - 2.0 * s2) / (n * n - n) / 4.0;
        s_c_sh = (float)(-1.0 / (bw0 * 0.6931471805599453 * 16.0));
    }
    __syncthreads();
    const float cs = s_c_sh;
    const float c2 = -2.f * cs;

    // B (column-tile) frags: resident in registers for the whole block
    bf16x8 bh[4][2], bl[4][2];
    float sbc[4];
    #pragma unroll
    for (int j = 0; j < 4; ++j) {
        const size_t rb = (size_t)(bc * 64 + j * 16 + lrow) * DIMS + quad * 8;
        bh[j][0] = *(const bf16x8*)(Xh + rb);
        bh[j][1] = *(const bf16x8*)(Xh + rb + 32);
        bl[j][0] = *(const bf16x8*)(Xl + rb);
        bl[j][1] = *(const bf16x8*)(Xl + rb + 32);
        sbc[j] = sqbuf[bc * 64 + j * 16 + lrow] * cs;
    }

    const size_t aoff = (size_t)(w * 16 + lrow) * DIMS + quad * 8;

    // prefetch first A-frags
    bf16x8 ah0 = *(const bf16x8*)(Xh + (size_t)r0 * 64 * DIMS + aoff);
    bf16x8 ah1 = *(const bf16x8*)(Xh + (size_t)r0 * 64 * DIMS + aoff + 32);
    bf16x8 al0 = *(const bf16x8*)(Xl + (size_t)r0 * 64 * DIMS + aoff);
    bf16x8 al1 = *(const bf16x8*)(Xl + (size_t)r0 * 64 * DIMS + aoff + 32);
    float4 sa4 = *(const float4*)(sqbuf + r0 * 64 + w * 16 + quad * 4);

    double dacc = 0.0;

    for (int r = r0; r <= r1; ++r) {
        bf16x8 cah0 = ah0, cah1 = ah1, cal0 = al0, cal1 = al1;
        float4 csa = sa4;
        int rn = (r < r1) ? r + 1 : r1;
        ah0 = *(const bf16x8*)(Xh + (size_t)rn * 64 * DIMS + aoff);
        ah1 = *(const bf16x8*)(Xh + (size_t)rn * 64 * DIMS + aoff + 32);
        al0 = *(const bf16x8*)(Xl + (size_t)rn * 64 * DIMS + aoff);
        al1 = *(const bf16x8*)(Xl + (size_t)rn * 64 * DIMS + aoff + 32);
        sa4 = *(const float4*)(sqbuf + rn * 64 + w * 16 + quad * 4);

        f32x4 acc[4];
        #pragma unroll
        for (int j = 0; j < 4; ++j) acc[j] = (f32x4){0.f, 0.f, 0.f, 0.f};
        #pragma unroll
        for (int j = 0; j < 4; ++j) {
            // dot = Ah·Bh + Ah·Bl + Al·Bh  (lo·lo dropped, ~2^-18 rel)
            acc[j] = __builtin_amdgcn_mfma_f32_16x16x32_bf16(cah0, bh[j][0], acc[j], 0, 0, 0);
            acc[j] = __builtin_amdgcn_mfma_f32_16x16x32_bf16(cah1, bh[j][1], acc[j], 0, 0, 0);
            acc[j] = __builtin_amdgcn_mfma_f32_16x16x32_bf16(cah0, bl[j][0], acc[j], 0, 0, 0);
            acc[j] = __builtin_amdgcn_mfma_f32_16x16x32_bf16(cah1, bl[j][1], acc[j], 0, 0, 0);
            acc[j] = __builtin_amdgcn_mfma_f32_16x16x32_bf16(cal0, bh[j][0], acc[j], 0, 0, 0);
            acc[j] = __builtin_amdgcn_mfma_f32_16x16x32_bf16(cal1, bh[j][1], acc[j], 0, 0, 0);
        }

        float sac[4] = {csa.x * cs, csa.y * cs, csa.z * cs, csa.w * cs};
        float lsum = 0.f;
        #pragma unroll
        for (int j = 0; j < 4; ++j) {
            #pragma unroll
            for (int p = 0; p < 4; ++p) {
                // t0 = -L2/(16*bw0*ln2); exp2 then 4 squarings = 5 kernels, 1 trans
                float t0 = fmaf(acc[j][p], c2, sac[p] + sbc[j]);
                float e4 = EXP2F(t0);
                float e3 = e4 * e4;
                float e2 = e3 * e3;
                float e1 = e2 * e2;
                float e0 = e1 * e1;
                lsum += ((e0 + e1) + (e2 + e3)) + e4;
            }
        }
        #pragma unroll
        for (int off = 32; off > 0; off >>= 1) lsum += __shfl_xor(lsum, off, 64);
        if (lane == 0) {
            float sgn = ((r < 64) == (bc < 64)) ? 1.f : -1.f;
            float wt  = (r == bc) ? 1.f : 2.f;
            dacc += (double)lsum * (double)(sgn * wt);
        }
    }

    if (lane == 0) s_wred[w] = dacc;
    __syncthreads();
    if (t == 0) {
        double bsum = (s_wred[0] + s_wred[1]) + (s_wred[2] + s_wred[3]);
        atomicAdd(grand, bsum);
        __threadfence();
        int prev = atomicAdd(cnt, 1);
        if (prev == LIVE_BLOCKS - 1) {       // last live block finalizes
            __threadfence();
            double g = atomicAdd(grand, 0.0);  // coherent read of the total
            out[0] = (float)(g / ((double)BATCH * (double)BATCH));
        }
    }
}

extern "C" void kernel_launch(void* const* d_in, const int* in_sizes, int n_in,
                              void* d_out, int out_size, void* d_ws, size_t ws_size,
                              hipStream_t stream) {
    const float* src = (const float*)d_in[0];
    const float* tgt = (const float*)d_in[1];
    char* ws = (char*)d_ws;
    double* wd    = (double*)ws;
    int*    cnt   = (int*)(ws + 528);
    float*  sqbuf = (float*)(ws + 544);
    short*  Xh    = (short*)(ws + 33312);
    short*  Xl    = (short*)(ws + 1081888);

    hipMemsetAsync(d_ws, 0, 544, stream);   // zero wd[0..65] + counter

    pass1_kernel<<<128, 256, 0, stream>>>(src, tgt, wd, sqbuf, Xh, Xl);

    dim3 grid(128, 16);
    pass2_kernel<<<grid, 256, 0, stream>>>(Xh, Xl, sqbuf, wd, &wd[65], cnt,
                                           (float*)d_out);
}